// Round 5
// baseline (3289.339 us; speedup 1.0000x reference)
//
#include <hip/hip_runtime.h>
#include <math.h>

typedef unsigned int u32;
typedef unsigned long long u64;

#define BIGN (-1e30f)

static constexpr int NB = 16;     // batch
static constexpr int TF = 2000;   // T_FEATS
static constexpr int TT = 400;    // T_TEXT

__device__ __forceinline__ float wsum(float v){
#pragma unroll
  for(int o=32;o;o>>=1) v += __shfl_xor(v,o,64);
  return v;
}
// log-sum-exp in BASE-2 domain (verified in Round 2)
__device__ __forceinline__ float lse2b(float x, float y){
  float m = fmaxf(x,y);
  return m + log2f(1.0f + exp2f(-fabsf(x-y)));
}
__device__ __forceinline__ float lse3b(float x, float y, float z){
  float m = fmaxf(fmaxf(x,y),z);
  return m + log2f(exp2f(x-m) + exp2f(y-m) + exp2f(z-m));
}

// ---------------- gammaln tables ----------------
__global__ void k_lgt(double* lgt){
  int m = blockIdx.x*blockDim.x + threadIdx.x;
  if(m < 2432) lgt[m] = (m>=1)? lgamma((double)m) : 0.0;
}
__global__ void k_terms(const double* __restrict__ lgt, double* rowA, double* colA, double* sA){
  int i = blockIdx.x*blockDim.x + threadIdx.x;
  if(i < TF)   rowA[i] = -lgt[2401] - lgt[i+1] - lgt[2000-i] + lgt[2001];
  if(i < TT)   colA[i] =  lgt[401]  - lgt[i+2] - lgt[400-i];
  if(i < 2399) sA[i]   =  lgt[i+2]  + lgt[2399-i];
}

// ---------------- conv1d (cross-correlation, pad=(KW-1)/2), OIH weights ----------------
template<int CIN, int KW, bool RELU>
__global__ __launch_bounds__(256) void conv_k(const float* __restrict__ in, const float* __restrict__ w,
    const float* __restrict__ bias, float* __restrict__ out, int P){
  constexpr int PT = 32;
  constexpr int ROWS = PT + KW - 1;
  constexpr int RPAD = (ROWS + 3) & ~3;
  __shared__ __align__(16) float xs[256][RPAD];
  const int b = blockIdx.y;
  const int p0 = blockIdx.x * PT;
  const int o = threadIdx.x;
  float acc[PT];
  const float bo = bias[o];
#pragma unroll
  for(int i=0;i<PT;i++) acc[i] = bo;
  const float* inb = in + (size_t)b * P * CIN;
  const float* wo  = w  + (size_t)o * CIN * KW;
  for(int cc=0; cc<CIN; cc+=256){
    __syncthreads();
    for(int i=0;i<ROWS;i++){
      int p = p0 + i - (KW==3 ? 1 : 0);
      float v = 0.f;
      if(p>=0 && p<P) v = inb[(size_t)p*CIN + cc + o];
      xs[o][i] = v;
    }
    __syncthreads();
    for(int c=0;c<256;c++){
      float win[RPAD];
#pragma unroll
      for(int q=0;q<RPAD/4;q++) ((float4*)win)[q] = ((const float4*)&xs[c][0])[q];
      if(KW==3){
        float w0 = wo[(size_t)(cc+c)*3+0];
        float w1 = wo[(size_t)(cc+c)*3+1];
        float w2 = wo[(size_t)(cc+c)*3+2];
#pragma unroll
        for(int i=0;i<PT;i++) acc[i] = fmaf(w2,win[i+2],fmaf(w1,win[i+1],fmaf(w0,win[i],acc[i])));
      } else {
        float w0 = wo[cc+c];
#pragma unroll
        for(int i=0;i<PT;i++) acc[i] = fmaf(w0,win[i],acc[i]);
      }
    }
  }
#pragma unroll
  for(int i=0;i<PT;i++){
    int p = p0+i;
    if(p<P){
      float v = acc[i];
      if(RELU) v = fmaxf(v,0.f);
      out[((size_t)b*P+p)*256 + o] = v;
    }
  }
}

// ---------------- row squared norms ----------------
__global__ __launch_bounds__(256) void norm2_k(const float* __restrict__ x, float* __restrict__ o, int rows){
  int r = blockIdx.x*4 + (threadIdx.x>>6);
  int lane = threadIdx.x & 63;
  if(r>=rows) return;
  float4 v = ((const float4*)(x + (size_t)r*256))[lane];
  float s = v.x*v.x + v.y*v.y + v.z*v.z + v.w*v.w;
  s = wsum(s);
  if(lane==0) o[r] = s;
}

// ---------------- score = -sqrt(max(||f||^2+||t||^2-2 f.t, 1e-12)) ----------------
__global__ __launch_bounds__(256) void score_gemm(const float* __restrict__ F, const float* __restrict__ Tn,
    const float* __restrict__ fn2, const float* __restrict__ tn2, float* __restrict__ outp){
  constexpr int KC = 32;
  __shared__ __align__(16) float As[KC][68];
  __shared__ __align__(16) float Bs[KC][68];
  const int b = blockIdx.z;
  const int t0 = blockIdx.y*64, s0 = blockIdx.x*64;
  const int tid = threadIdx.x, tx = tid&15, ty = tid>>4;
  const float* Fb = F  + (size_t)b*TF*256;
  const float* Tb = Tn + (size_t)b*TT*256;
  float acc[4][4] = {};
  const int lk = tid & 31, lt0 = (tid>>5)*8;
  for(int k0=0;k0<256;k0+=KC){
    __syncthreads();
#pragma unroll
    for(int i=0;i<8;i++){
      int t = t0 + lt0 + i;
      As[lk][lt0+i] = (t<TF)? Fb[(size_t)t*256 + k0 + lk] : 0.f;
      int s = s0 + lt0 + i;
      Bs[lk][lt0+i] = (s<TT)? Tb[(size_t)s*256 + k0 + lk] : 0.f;
    }
    __syncthreads();
#pragma unroll
    for(int k=0;k<KC;k++){
      float a0[4], b0[4];
      *(float4*)a0 = *(const float4*)&As[k][ty*4];
      *(float4*)b0 = *(const float4*)&Bs[k][tx*4];
#pragma unroll
      for(int i=0;i<4;i++)
#pragma unroll
        for(int j=0;j<4;j++) acc[i][j] = fmaf(a0[i], b0[j], acc[i][j]);
    }
  }
#pragma unroll
  for(int i=0;i<4;i++){
    int t = t0 + ty*4 + i;
    if(t<TF){
      float fn = fn2[b*TF + t];
#pragma unroll
      for(int j=0;j<4;j++){
        int s = s0 + tx*4 + j;
        if(s<TT){
          float d2 = fn + tn2[b*TT + s] - 2.f*acc[i][j];
          outp[((size_t)b*TF + t)*TT + s] = -sqrtf(fmaxf(d2, 1e-12f));
        }
      }
    }
  }
}

// ---------------- per-row log_softmax + prior, and Z2 = logsumexp([BLANK, row]) ----------------
__global__ __launch_bounds__(128) void softmax_prior_k(float* __restrict__ logp,
    const double* __restrict__ rowA, const double* __restrict__ colA, const double* __restrict__ sA,
    float* __restrict__ Z2){
  const int row = blockIdx.x;           // b*TF + t0
  const int t0 = row % TF;
  float* rp = logp + (size_t)row*TT;
  const int tid = threadIdx.x;
  __shared__ float sh2[2];
  float v[4]; int ix[4];
#pragma unroll
  for(int i=0;i<4;i++){ ix[i] = tid + i*128; v[i] = (ix[i]<TT)? rp[ix[i]] : BIGN; }
  float m = fmaxf(fmaxf(v[0],v[1]),fmaxf(v[2],v[3]));
#pragma unroll
  for(int o=32;o;o>>=1) m = fmaxf(m, __shfl_xor(m,o,64));
  if((tid&63)==0) sh2[tid>>6] = m;
  __syncthreads();
  m = fmaxf(sh2[0], sh2[1]);
  float s = 0.f;
#pragma unroll
  for(int i=0;i<4;i++) if(ix[i]<TT) s += expf(v[i]-m);
  s = wsum(s);
  __syncthreads();
  if((tid&63)==0) sh2[tid>>6] = s;
  __syncthreads();
  s = sh2[0] + sh2[1];
  const float lse = m + logf(s);
  const double rA = rowA[t0];
  float f[4]; float m2 = BIGN;
#pragma unroll
  for(int i=0;i<4;i++){
    if(ix[i]<TT){
      float pr = (float)(colA[ix[i]] + sA[t0+ix[i]] + rA);
      f[i] = (v[i]-lse) + pr;
      rp[ix[i]] = f[i];
      m2 = fmaxf(m2, f[i]);
    } else f[i] = BIGN;
  }
#pragma unroll
  for(int o=32;o;o>>=1) m2 = fmaxf(m2, __shfl_xor(m2,o,64));
  __syncthreads();
  if((tid&63)==0) sh2[tid>>6] = m2;
  __syncthreads();
  m2 = fmaxf(fmaxf(sh2[0],sh2[1]), -1.0f);
  float s2 = (tid==0)? expf(-1.0f - m2) : 0.f;
#pragma unroll
  for(int i=0;i<4;i++) if(ix[i]<TT) s2 += expf(f[i]-m2);
  s2 = wsum(s2);
  __syncthreads();
  if((tid&63)==0) sh2[tid>>6] = s2;
  __syncthreads();
  if(tid==0) Z2[row] = m2 + logf(sh2[0]+sh2[1]);
}

// ---------------- single-wave scans: CTC forward (log2 domain, Round-2-verified math) + MAS ----------------
// CTC: 14 states/lane (s=14*lane+i). alpha' = alpha + cumZ (Z dropped, subtracted once at end).
//   Log domain tolerates the e^1000+ cross-state dynamic range that sank the linear-domain variants.
// MAS: 7 states/lane, cmp bits packed 1 byte/lane/step.
#define LCTC_STEP(EBU) { \
  float n1 = __shfl_up(a[13], 1); \
  if(lane==0) n1 = BIGN; \
  a[13] = lse3b(a[13], a[12], a[11]) + (EBU)[6]; \
  a[12] = lse2b(a[12], a[11]) + EBL; \
  a[11] = lse3b(a[11], a[10], a[9]) + (EBU)[5]; \
  a[10] = lse2b(a[10], a[9]) + EBL; \
  a[9]  = lse3b(a[9],  a[8],  a[7]) + (EBU)[4]; \
  a[8]  = lse2b(a[8],  a[7]) + EBL; \
  a[7]  = lse3b(a[7],  a[6],  a[5]) + (EBU)[3]; \
  a[6]  = lse2b(a[6],  a[5]) + EBL; \
  a[5]  = lse3b(a[5],  a[4],  a[3]) + (EBU)[2]; \
  a[4]  = lse2b(a[4],  a[3]) + EBL; \
  a[3]  = lse3b(a[3],  a[2],  a[1]) + (EBU)[1]; \
  a[2]  = lse2b(a[2],  a[1]) + EBL; \
  a[1]  = lse3b(a[1],  a[0],  n1) + (EBU)[0]; \
  a[0]  = lse2b(a[0],  n1) + EBL; }

#define MAS_STEP(EBU, TIDX) { \
  float n1 = __shfl_up(q[6],1); \
  u32 byte = 0; \
  if(lane>0 && n1 >= q[0]) byte |= 1u; \
  if(q[0] >= q[1]) byte |= 2u; \
  if(q[1] >= q[2]) byte |= 4u; \
  if(q[2] >= q[3]) byte |= 8u; \
  if(q[3] >= q[4]) byte |= 16u; \
  if(q[4] >= q[5]) byte |= 32u; \
  if(q[5] >= q[6]) byte |= 64u; \
  cb[(size_t)((TIDX)-1)*64 + lane] = (unsigned char)byte; \
  q[6] = fmaxf(q[6], q[5]) + (EBU)[6]; \
  q[5] = fmaxf(q[5], q[4]) + (EBU)[5]; \
  q[4] = fmaxf(q[4], q[3]) + (EBU)[4]; \
  q[3] = fmaxf(q[3], q[2]) + (EBU)[3]; \
  q[2] = fmaxf(q[2], q[1]) + (EBU)[2]; \
  q[1] = fmaxf(q[1], q[0]) + (EBU)[1]; \
  q[0] = fmaxf(q[0], (lane>0)? n1 : BIGN) + (EBU)[0]; }

__global__ __launch_bounds__(64,1) void scan_k(const float* __restrict__ logp,
    const float* __restrict__ Z2, unsigned char* __restrict__ cmpb, float* __restrict__ nll){
  const int lane = threadIdx.x;
  constexpr float IL2 = 1.4426950408889634f;   // 1/ln2
  constexpr float L2  = 0.6931471805599453f;   // ln2
  if(blockIdx.x < NB){
    const int b = blockIdx.x;
    const float* lp = logp + (size_t)b*TF*TT;
    double zs = 0.0;
    for(int t=lane; t<TF; t+=64) zs += (double)Z2[b*TF + t];
#pragma unroll
    for(int o=32;o;o>>=1) zs += __shfl_xor(zs, o, 64);
    int jc[7];
#pragma unroll
    for(int i=0;i<7;i++){ int j = 7*lane + i; jc[i] = (j < TT)? j : (TT-1); }
    float a[14];
#pragma unroll
    for(int i=0;i<14;i++) a[i] = BIGN;
    if(lane==0){ a[0] = -1.0f*IL2; a[1] = lp[0]*IL2; }
    const float EBL = -1.0f*IL2;
    float eb[8][7];
#pragma unroll
    for(int u=0;u<8;u++){
#pragma unroll
      for(int i=0;i<7;i++) eb[u][i] = lp[(size_t)(1+u)*TT + jc[i]] * IL2;
    }
    int t0 = 1;
    for(; t0 + 8 <= TF; t0 += 8){
#pragma unroll
      for(int u=0;u<8;u++){
        LCTC_STEP(eb[u]);
        int rn = t0+u+8; if(rn > TF-1) rn = TF-1;
#pragma unroll
        for(int i=0;i<7;i++) eb[u][i] = lp[(size_t)rn*TT + jc[i]] * IL2;
      }
    }
    for(; t0<TF; t0++){     // short tail, direct loads
      float P[7];
#pragma unroll
      for(int i=0;i<7;i++) P[i] = lp[(size_t)t0*TT + jc[i]] * IL2;
      LCTC_STEP(P);
    }
    if(lane==57){
      float r = lse2b(a[2], a[1]) * L2;  // states 800, 799
      nll[b] = -(r - (float)zs);
    }
  } else {
    const int b = blockIdx.x - NB;
    const float* lp = logp + (size_t)b*TF*TT;
    unsigned char* cb = cmpb + (size_t)b*TF*64;
    int jc[7];
#pragma unroll
    for(int i=0;i<7;i++){ int j = 7*lane + i; jc[i] = (j < TT)? j : (TT-1); }
    float q[7];
#pragma unroll
    for(int i=0;i<7;i++) q[i] = BIGN;
    if(lane==0) q[0] = lp[0];
    float eb[8][7];
#pragma unroll
    for(int u=0;u<8;u++){
#pragma unroll
      for(int i=0;i<7;i++) eb[u][i] = lp[(size_t)(1+u)*TT + jc[i]];
    }
    int t0 = 1;
    for(; t0 + 8 <= TF; t0 += 8){
#pragma unroll
      for(int u=0;u<8;u++){
        MAS_STEP(eb[u], t0+u);
        int rn = t0+u+8; if(rn > TF-1) rn = TF-1;
#pragma unroll
        for(int i=0;i<7;i++) eb[u][i] = lp[(size_t)rn*TT + jc[i]];
      }
    }
    for(; t0<TF; t0++){
      float P[7];
#pragma unroll
      for(int i=0;i<7;i++) P[i] = lp[(size_t)t0*TT + jc[i]];
      MAS_STEP(P, t0);
    }
    // final row of cmp bits (row TF-1)
    {
      float n1 = __shfl_up(q[6],1);
      u32 byte = 0;
      if(lane>0 && n1 >= q[0]) byte |= 1u;
      if(q[0] >= q[1]) byte |= 2u;
      if(q[1] >= q[2]) byte |= 4u;
      if(q[2] >= q[3]) byte |= 8u;
      if(q[3] >= q[4]) byte |= 16u;
      if(q[4] >= q[5]) byte |= 32u;
      if(q[5] >= q[6]) byte |= 64u;
      cb[(size_t)(TF-1)*64 + lane] = (unsigned char)byte;
    }
  }
}

// ---------------- MAS backtrack + ds + gather ----------------
__global__ __launch_bounds__(256) void masback_k(const unsigned char* __restrict__ cmpb,
    const float* __restrict__ logp, float* __restrict__ ds, float* __restrict__ gsum){
  const int b = blockIdx.x;
  const unsigned char* cb = cmpb + (size_t)b*TF*64;
  __shared__ unsigned char bits[500*64];
  __shared__ short Ash[TF];
  __shared__ int cnt[TT];
  __shared__ float ps[4];
  int a = TT-1;
  for(int ch=3; ch>=0; ch--){
    const int tlo = ch*500;
    __syncthreads();
    for(int i=threadIdx.x;i<8000;i+=256) ((u32*)bits)[i] = ((const u32*)(cb + (size_t)tlo*64))[i];
    __syncthreads();
    if(threadIdx.x==0){
      int thi = tlo + 499;
      if(ch==3){ Ash[TF-1] = (short)(TT-1); thi = TF-2; }
      for(int t=thi;t>=tlo;t--){
        if(a > 0){
          unsigned char w = bits[(t-tlo)*64 + a/7];
          a -= (int)((w >> (a%7)) & 1u);
        }
        Ash[t] = (short)a;
      }
    }
  }
  __syncthreads();
  for(int i=threadIdx.x;i<TT;i+=256) cnt[i]=0;
  __syncthreads();
  float part = 0.f;
  const float* lp = logp + (size_t)b*TF*TT;
  for(int t=threadIdx.x;t<TF;t+=256){
    int at = Ash[t];
    atomicAdd(&cnt[at], 1);
    part += lp[(size_t)t*TT + at];
  }
  __syncthreads();
  for(int i=threadIdx.x;i<TT;i+=256) ds[(size_t)b*TT + i] = (float)cnt[i];
  part = wsum(part);
  if((threadIdx.x&63)==0) ps[threadIdx.x>>6] = part;
  __syncthreads();
  if(threadIdx.x==0) gsum[b] = ps[0]+ps[1]+ps[2]+ps[3];
}

__global__ void final_k(const float* __restrict__ nll, const float* __restrict__ gsum, float* __restrict__ out){
  if(threadIdx.x==0 && blockIdx.x==0){
    float fs=0.f, bs=0.f;
    for(int b=0;b<NB;b++){ fs += nll[b] / (float)TT; bs += gsum[b] / (float)TF; }
    out[6400] = -(bs / (float)NB);   // bin_loss
    out[6401] = fs / (float)NB;      // forwardsum_loss
  }
}

extern "C" void kernel_launch(void* const* d_in, const int* in_sizes, int n_in,
                              void* d_out, int out_size, void* d_ws, size_t ws_size,
                              hipStream_t stream){
  const float* speech = (const float*)d_in[0];
  const float* txt    = (const float*)d_in[1];
  const float* tw1 = (const float*)d_in[4];
  const float* tb1 = (const float*)d_in[5];
  const float* tw2 = (const float*)d_in[6];
  const float* tb2 = (const float*)d_in[7];
  const float* fw1 = (const float*)d_in[8];
  const float* fb1 = (const float*)d_in[9];
  const float* fw2 = (const float*)d_in[10];
  const float* fb2 = (const float*)d_in[11];
  const float* fw3 = (const float*)d_in[12];
  const float* fb3 = (const float*)d_in[13];
  float* out  = (float*)d_out;
  float* ds   = out;                 // (16,400)
  float* logp = out + 6402;          // (16,2000,400)
  char* ws = (char*)d_ws;
  double* lgt  = (double*)(ws + 0);
  double* rowA = (double*)(ws + 20480);
  double* colA = (double*)(ws + 36864);
  double* sA   = (double*)(ws + 40960);
  float*  nll  = (float*)(ws + 61440);
  float*  gsum = (float*)(ws + 61696);
  float*  Z2   = (float*)(ws + 65536);
  float*  fn2  = (float*)(ws + 196608);
  float*  tn2  = (float*)(ws + 327680);
  unsigned char* cmpb = (unsigned char*)(ws + 360448);
  float*  tenc = (float*)(ws + 2408448);
  float*  f1   = (float*)(ws + 8962048);
  float*  t1   = f1;      // t1 dead before f1 (f-conv1 out) is written
  float*  f2   = logp;    // f-conv2 intermediate; dead before scores written
  if(ws_size < 41730048) return;

  k_lgt  <<<10,256,0,stream>>>(lgt);
  k_terms<<<10,256,0,stream>>>(lgt,rowA,colA,sA);

  conv_k<256,3,true ><<<dim3(13,NB),256,0,stream>>>(txt, tw1, tb1, t1, TT);
  conv_k<256,1,false><<<dim3(13,NB),256,0,stream>>>(t1, tw2, tb2, tenc, TT);
  conv_k<512,3,true ><<<dim3(63,NB),256,0,stream>>>(speech, fw1, fb1, f1, TF);
  conv_k<256,3,true ><<<dim3(63,NB),256,0,stream>>>(f1, fw2, fb2, f2, TF);
  conv_k<256,1,false><<<dim3(63,NB),256,0,stream>>>(f2, fw3, fb3, f1, TF);

  norm2_k<<<(NB*TF)/4,256,0,stream>>>(f1, fn2, NB*TF);
  norm2_k<<<(NB*TT)/4,256,0,stream>>>(tenc, tn2, NB*TT);

  score_gemm<<<dim3(7,32,NB),256,0,stream>>>(f1, tenc, fn2, tn2, logp);
  softmax_prior_k<<<NB*TF,128,0,stream>>>(logp, rowA, colA, sA, Z2);

  scan_k<<<2*NB,64,0,stream>>>(logp, Z2, cmpb, nll);
  masback_k<<<NB,256,0,stream>>>(cmpb, logp, ds, gsum);
  final_k<<<1,64,0,stream>>>(nll, gsum, out);
}

// Round 6
// 2834.401 us; speedup vs baseline: 1.1605x; 1.1605x over previous
//
#include <hip/hip_runtime.h>
#include <math.h>

typedef unsigned int u32;
typedef unsigned long long u64;

#define BIGN (-1e30f)

static constexpr int NB = 16;     // batch
static constexpr int TF = 2000;   // T_FEATS
static constexpr int TT = 400;    // T_TEXT

__device__ __forceinline__ float wsum(float v){
#pragma unroll
  for(int o=32;o;o>>=1) v += __shfl_xor(v,o,64);
  return v;
}
// log-sum-exp in BASE-2 domain; lse3b via med3/min3: one exp2 is exp2(0)=1 always.
__device__ __forceinline__ float lse2b(float x, float y){
  float m = fmaxf(x,y);
  return m + log2f(1.0f + exp2f(-fabsf(x-y)));
}
__device__ __forceinline__ float lse3b(float x, float y, float z){
  float mx = fmaxf(fmaxf(x,y),z);
  float md = __builtin_amdgcn_fmed3f(x,y,z);
  float mn = fminf(fminf(x,y),z);
  return mx + log2f(1.0f + exp2f(md-mx) + exp2f(mn-mx));
}

// ---------------- gammaln tables ----------------
__global__ void k_lgt(double* lgt){
  int m = blockIdx.x*blockDim.x + threadIdx.x;
  if(m < 2432) lgt[m] = (m>=1)? lgamma((double)m) : 0.0;
}
__global__ void k_terms(const double* __restrict__ lgt, double* rowA, double* colA, double* sA){
  int i = blockIdx.x*blockDim.x + threadIdx.x;
  if(i < TF)   rowA[i] = -lgt[2401] - lgt[i+1] - lgt[2000-i] + lgt[2001];
  if(i < TT)   colA[i] =  lgt[401]  - lgt[i+2] - lgt[400-i];
  if(i < 2399) sA[i]   =  lgt[i+2]  + lgt[2399-i];
}

// ---------------- conv1d (cross-correlation, pad=(KW-1)/2), OIH weights ----------------
template<int CIN, int KW, bool RELU>
__global__ __launch_bounds__(256) void conv_k(const float* __restrict__ in, const float* __restrict__ w,
    const float* __restrict__ bias, float* __restrict__ out, int P){
  constexpr int PT = 32;
  constexpr int ROWS = PT + KW - 1;
  constexpr int RPAD = (ROWS + 3) & ~3;
  __shared__ __align__(16) float xs[256][RPAD];
  const int b = blockIdx.y;
  const int p0 = blockIdx.x * PT;
  const int o = threadIdx.x;
  float acc[PT];
  const float bo = bias[o];
#pragma unroll
  for(int i=0;i<PT;i++) acc[i] = bo;
  const float* inb = in + (size_t)b * P * CIN;
  const float* wo  = w  + (size_t)o * CIN * KW;
  for(int cc=0; cc<CIN; cc+=256){
    __syncthreads();
    for(int i=0;i<ROWS;i++){
      int p = p0 + i - (KW==3 ? 1 : 0);
      float v = 0.f;
      if(p>=0 && p<P) v = inb[(size_t)p*CIN + cc + o];
      xs[o][i] = v;
    }
    __syncthreads();
    for(int c=0;c<256;c++){
      float win[RPAD];
#pragma unroll
      for(int q=0;q<RPAD/4;q++) ((float4*)win)[q] = ((const float4*)&xs[c][0])[q];
      if(KW==3){
        float w0 = wo[(size_t)(cc+c)*3+0];
        float w1 = wo[(size_t)(cc+c)*3+1];
        float w2 = wo[(size_t)(cc+c)*3+2];
#pragma unroll
        for(int i=0;i<PT;i++) acc[i] = fmaf(w2,win[i+2],fmaf(w1,win[i+1],fmaf(w0,win[i],acc[i])));
      } else {
        float w0 = wo[cc+c];
#pragma unroll
        for(int i=0;i<PT;i++) acc[i] = fmaf(w0,win[i],acc[i]);
      }
    }
  }
#pragma unroll
  for(int i=0;i<PT;i++){
    int p = p0+i;
    if(p<P){
      float v = acc[i];
      if(RELU) v = fmaxf(v,0.f);
      out[((size_t)b*P+p)*256 + o] = v;
    }
  }
}

// ---------------- row squared norms ----------------
__global__ __launch_bounds__(256) void norm2_k(const float* __restrict__ x, float* __restrict__ o, int rows){
  int r = blockIdx.x*4 + (threadIdx.x>>6);
  int lane = threadIdx.x & 63;
  if(r>=rows) return;
  float4 v = ((const float4*)(x + (size_t)r*256))[lane];
  float s = v.x*v.x + v.y*v.y + v.z*v.z + v.w*v.w;
  s = wsum(s);
  if(lane==0) o[r] = s;
}

// ---------------- score = -sqrt(max(||f||^2+||t||^2-2 f.t, 1e-12)) ----------------
__global__ __launch_bounds__(256) void score_gemm(const float* __restrict__ F, const float* __restrict__ Tn,
    const float* __restrict__ fn2, const float* __restrict__ tn2, float* __restrict__ outp){
  constexpr int KC = 32;
  __shared__ __align__(16) float As[KC][68];
  __shared__ __align__(16) float Bs[KC][68];
  const int b = blockIdx.z;
  const int t0 = blockIdx.y*64, s0 = blockIdx.x*64;
  const int tid = threadIdx.x, tx = tid&15, ty = tid>>4;
  const float* Fb = F  + (size_t)b*TF*256;
  const float* Tb = Tn + (size_t)b*TT*256;
  float acc[4][4] = {};
  const int lk = tid & 31, lt0 = (tid>>5)*8;
  for(int k0=0;k0<256;k0+=KC){
    __syncthreads();
#pragma unroll
    for(int i=0;i<8;i++){
      int t = t0 + lt0 + i;
      As[lk][lt0+i] = (t<TF)? Fb[(size_t)t*256 + k0 + lk] : 0.f;
      int s = s0 + lt0 + i;
      Bs[lk][lt0+i] = (s<TT)? Tb[(size_t)s*256 + k0 + lk] : 0.f;
    }
    __syncthreads();
#pragma unroll
    for(int k=0;k<KC;k++){
      float a0[4], b0[4];
      *(float4*)a0 = *(const float4*)&As[k][ty*4];
      *(float4*)b0 = *(const float4*)&Bs[k][tx*4];
#pragma unroll
      for(int i=0;i<4;i++)
#pragma unroll
        for(int j=0;j<4;j++) acc[i][j] = fmaf(a0[i], b0[j], acc[i][j]);
    }
  }
#pragma unroll
  for(int i=0;i<4;i++){
    int t = t0 + ty*4 + i;
    if(t<TF){
      float fn = fn2[b*TF + t];
#pragma unroll
      for(int j=0;j<4;j++){
        int s = s0 + tx*4 + j;
        if(s<TT){
          float d2 = fn + tn2[b*TT + s] - 2.f*acc[i][j];
          outp[((size_t)b*TF + t)*TT + s] = -sqrtf(fmaxf(d2, 1e-12f));
        }
      }
    }
  }
}

// ---------------- per-row log_softmax + prior, and Z2 = logsumexp([BLANK, row]) ----------------
__global__ __launch_bounds__(128) void softmax_prior_k(float* __restrict__ logp,
    const double* __restrict__ rowA, const double* __restrict__ colA, const double* __restrict__ sA,
    float* __restrict__ Z2){
  const int row = blockIdx.x;           // b*TF + t0
  const int t0 = row % TF;
  float* rp = logp + (size_t)row*TT;
  const int tid = threadIdx.x;
  __shared__ float sh2[2];
  float v[4]; int ix[4];
#pragma unroll
  for(int i=0;i<4;i++){ ix[i] = tid + i*128; v[i] = (ix[i]<TT)? rp[ix[i]] : BIGN; }
  float m = fmaxf(fmaxf(v[0],v[1]),fmaxf(v[2],v[3]));
#pragma unroll
  for(int o=32;o;o>>=1) m = fmaxf(m, __shfl_xor(m,o,64));
  if((tid&63)==0) sh2[tid>>6] = m;
  __syncthreads();
  m = fmaxf(sh2[0], sh2[1]);
  float s = 0.f;
#pragma unroll
  for(int i=0;i<4;i++) if(ix[i]<TT) s += expf(v[i]-m);
  s = wsum(s);
  __syncthreads();
  if((tid&63)==0) sh2[tid>>6] = s;
  __syncthreads();
  s = sh2[0] + sh2[1];
  const float lse = m + logf(s);
  const double rA = rowA[t0];
  float f[4]; float m2 = BIGN;
#pragma unroll
  for(int i=0;i<4;i++){
    if(ix[i]<TT){
      float pr = (float)(colA[ix[i]] + sA[t0+ix[i]] + rA);
      f[i] = (v[i]-lse) + pr;
      rp[ix[i]] = f[i];
      m2 = fmaxf(m2, f[i]);
    } else f[i] = BIGN;
  }
#pragma unroll
  for(int o=32;o;o>>=1) m2 = fmaxf(m2, __shfl_xor(m2,o,64));
  __syncthreads();
  if((tid&63)==0) sh2[tid>>6] = m2;
  __syncthreads();
  m2 = fmaxf(fmaxf(sh2[0],sh2[1]), -1.0f);
  float s2 = (tid==0)? expf(-1.0f - m2) : 0.f;
#pragma unroll
  for(int i=0;i<4;i++) if(ix[i]<TT) s2 += expf(f[i]-m2);
  s2 = wsum(s2);
  __syncthreads();
  if((tid&63)==0) sh2[tid>>6] = s2;
  __syncthreads();
  if(tid==0) Z2[row] = m2 + logf(sh2[0]+sh2[1]);
}

// ---------------- single-wave scans: CTC forward (log2 domain) + MAS ----------------
// Explicit 8x-unrolled software pipeline, named prefetch arrays (all indices compile-time),
// amdgpu_waves_per_eu(1,1): allocator may use full VGPR file (1 wave/CU anyway).
#define LCTC_STEP(E) { \
  float n1 = __shfl_up(a[13], 1); \
  if(lane==0) n1 = BIGN; \
  a[13] = lse3b(a[13], a[12], a[11]) + (E)[6]; \
  a[12] = lse2b(a[12], a[11]) + EBL; \
  a[11] = lse3b(a[11], a[10], a[9]) + (E)[5]; \
  a[10] = lse2b(a[10], a[9]) + EBL; \
  a[9]  = lse3b(a[9],  a[8],  a[7]) + (E)[4]; \
  a[8]  = lse2b(a[8],  a[7]) + EBL; \
  a[7]  = lse3b(a[7],  a[6],  a[5]) + (E)[3]; \
  a[6]  = lse2b(a[6],  a[5]) + EBL; \
  a[5]  = lse3b(a[5],  a[4],  a[3]) + (E)[2]; \
  a[4]  = lse2b(a[4],  a[3]) + EBL; \
  a[3]  = lse3b(a[3],  a[2],  a[1]) + (E)[1]; \
  a[2]  = lse2b(a[2],  a[1]) + EBL; \
  a[1]  = lse3b(a[1],  a[0],  n1) + (E)[0]; \
  a[0]  = lse2b(a[0],  n1) + EBL; }

#define CPREF(E, ROW) { int rr=(ROW); rr = (rr>TF-1)? (TF-1) : rr; const float* rpp = lp + (size_t)rr*TT; \
  (E)[0]=rpp[jc[0]]*IL2; (E)[1]=rpp[jc[1]]*IL2; (E)[2]=rpp[jc[2]]*IL2; (E)[3]=rpp[jc[3]]*IL2; \
  (E)[4]=rpp[jc[4]]*IL2; (E)[5]=rpp[jc[5]]*IL2; (E)[6]=rpp[jc[6]]*IL2; }

#define MAS_STEP(E, TIDX) { \
  float n1 = __shfl_up(q[6],1); \
  u32 byte = 0; \
  if(lane>0 && n1 >= q[0]) byte |= 1u; \
  if(q[0] >= q[1]) byte |= 2u; \
  if(q[1] >= q[2]) byte |= 4u; \
  if(q[2] >= q[3]) byte |= 8u; \
  if(q[3] >= q[4]) byte |= 16u; \
  if(q[4] >= q[5]) byte |= 32u; \
  if(q[5] >= q[6]) byte |= 64u; \
  cb[(size_t)((TIDX)-1)*64 + lane] = (unsigned char)byte; \
  q[6] = fmaxf(q[6], q[5]) + (E)[6]; \
  q[5] = fmaxf(q[5], q[4]) + (E)[5]; \
  q[4] = fmaxf(q[4], q[3]) + (E)[4]; \
  q[3] = fmaxf(q[3], q[2]) + (E)[3]; \
  q[2] = fmaxf(q[2], q[1]) + (E)[2]; \
  q[1] = fmaxf(q[1], q[0]) + (E)[1]; \
  q[0] = fmaxf(q[0], (lane>0)? n1 : BIGN) + (E)[0]; }

#define MPREF(E, ROW) { int rr=(ROW); rr = (rr>TF-1)? (TF-1) : rr; const float* rpp = lp + (size_t)rr*TT; \
  (E)[0]=rpp[jc[0]]; (E)[1]=rpp[jc[1]]; (E)[2]=rpp[jc[2]]; (E)[3]=rpp[jc[3]]; \
  (E)[4]=rpp[jc[4]]; (E)[5]=rpp[jc[5]]; (E)[6]=rpp[jc[6]]; }

__global__ __launch_bounds__(64) __attribute__((amdgpu_waves_per_eu(1,1)))
void scan_k(const float* __restrict__ logp,
    const float* __restrict__ Z2, unsigned char* __restrict__ cmpb, float* __restrict__ nll){
  const int lane = threadIdx.x;
  constexpr float IL2 = 1.4426950408889634f;   // 1/ln2
  constexpr float L2  = 0.6931471805599453f;   // ln2
  if(blockIdx.x < NB){
    const int b = blockIdx.x;
    const float* lp = logp + (size_t)b*TF*TT;
    double zs = 0.0;
    for(int t=lane; t<TF; t+=64) zs += (double)Z2[b*TF + t];
#pragma unroll
    for(int o=32;o;o>>=1) zs += __shfl_xor(zs, o, 64);
    int jc[7];
#pragma unroll
    for(int i=0;i<7;i++){ int j = 7*lane + i; jc[i] = (j < TT)? j : (TT-1); }
    float a[14];
#pragma unroll
    for(int i=0;i<14;i++) a[i] = BIGN;
    if(lane==0){ a[0] = -1.0f*IL2; a[1] = lp[0]*IL2; }
    const float EBL = -1.0f*IL2;
    float e0[7],e1[7],e2[7],e3[7],e4[7],e5[7],e6[7],e7[7];
    CPREF(e0,1); CPREF(e1,2); CPREF(e2,3); CPREF(e3,4);
    CPREF(e4,5); CPREF(e5,6); CPREF(e6,7); CPREF(e7,8);
    int t0 = 1;
    for(; t0 + 8 <= TF; t0 += 8){
      LCTC_STEP(e0); CPREF(e0, t0+8);
      LCTC_STEP(e1); CPREF(e1, t0+9);
      LCTC_STEP(e2); CPREF(e2, t0+10);
      LCTC_STEP(e3); CPREF(e3, t0+11);
      LCTC_STEP(e4); CPREF(e4, t0+12);
      LCTC_STEP(e5); CPREF(e5, t0+13);
      LCTC_STEP(e6); CPREF(e6, t0+14);
      LCTC_STEP(e7); CPREF(e7, t0+15);
    }
    for(; t0<TF; t0++){     // short tail, direct loads
      float P[7];
      CPREF(P, t0);
      LCTC_STEP(P);
    }
    if(lane==57){
      float r = lse2b(a[2], a[1]) * L2;  // states 800, 799
      nll[b] = -(r - (float)zs);
    }
  } else {
    const int b = blockIdx.x - NB;
    const float* lp = logp + (size_t)b*TF*TT;
    unsigned char* cb = cmpb + (size_t)b*TF*64;
    int jc[7];
#pragma unroll
    for(int i=0;i<7;i++){ int j = 7*lane + i; jc[i] = (j < TT)? j : (TT-1); }
    float q[7];
#pragma unroll
    for(int i=0;i<7;i++) q[i] = BIGN;
    if(lane==0) q[0] = lp[0];
    float e0[7],e1[7],e2[7],e3[7];
    MPREF(e0,1); MPREF(e1,2); MPREF(e2,3); MPREF(e3,4);
    int t0 = 1;
    for(; t0 + 4 <= TF; t0 += 4){
      MAS_STEP(e0, t0);   MPREF(e0, t0+4);
      MAS_STEP(e1, t0+1); MPREF(e1, t0+5);
      MAS_STEP(e2, t0+2); MPREF(e2, t0+6);
      MAS_STEP(e3, t0+3); MPREF(e3, t0+7);
    }
    for(; t0<TF; t0++){
      float P[7];
      MPREF(P, t0);
      MAS_STEP(P, t0);
    }
    // final row of cmp bits (row TF-1)
    {
      float n1 = __shfl_up(q[6],1);
      u32 byte = 0;
      if(lane>0 && n1 >= q[0]) byte |= 1u;
      if(q[0] >= q[1]) byte |= 2u;
      if(q[1] >= q[2]) byte |= 4u;
      if(q[2] >= q[3]) byte |= 8u;
      if(q[3] >= q[4]) byte |= 16u;
      if(q[4] >= q[5]) byte |= 32u;
      if(q[5] >= q[6]) byte |= 64u;
      cb[(size_t)(TF-1)*64 + lane] = (unsigned char)byte;
    }
  }
}

// ---------------- MAS backtrack + ds + gather ----------------
__global__ __launch_bounds__(256) void masback_k(const unsigned char* __restrict__ cmpb,
    const float* __restrict__ logp, float* __restrict__ ds, float* __restrict__ gsum){
  const int b = blockIdx.x;
  const unsigned char* cb = cmpb + (size_t)b*TF*64;
  __shared__ unsigned char bits[500*64];
  __shared__ short Ash[TF];
  __shared__ int cnt[TT];
  __shared__ float ps[4];
  int a = TT-1;
  for(int ch=3; ch>=0; ch--){
    const int tlo = ch*500;
    __syncthreads();
    for(int i=threadIdx.x;i<8000;i+=256) ((u32*)bits)[i] = ((const u32*)(cb + (size_t)tlo*64))[i];
    __syncthreads();
    if(threadIdx.x==0){
      int thi = tlo + 499;
      if(ch==3){ Ash[TF-1] = (short)(TT-1); thi = TF-2; }
      for(int t=thi;t>=tlo;t--){
        if(a > 0){
          unsigned char w = bits[(t-tlo)*64 + a/7];
          a -= (int)((w >> (a%7)) & 1u);
        }
        Ash[t] = (short)a;
      }
    }
  }
  __syncthreads();
  for(int i=threadIdx.x;i<TT;i+=256) cnt[i]=0;
  __syncthreads();
  float part = 0.f;
  const float* lp = logp + (size_t)b*TF*TT;
  for(int t=threadIdx.x;t<TF;t+=256){
    int at = Ash[t];
    atomicAdd(&cnt[at], 1);
    part += lp[(size_t)t*TT + at];
  }
  __syncthreads();
  for(int i=threadIdx.x;i<TT;i+=256) ds[(size_t)b*TT + i] = (float)cnt[i];
  part = wsum(part);
  if((threadIdx.x&63)==0) ps[threadIdx.x>>6] = part;
  __syncthreads();
  if(threadIdx.x==0) gsum[b] = ps[0]+ps[1]+ps[2]+ps[3];
}

__global__ void final_k(const float* __restrict__ nll, const float* __restrict__ gsum, float* __restrict__ out){
  if(threadIdx.x==0 && blockIdx.x==0){
    float fs=0.f, bs=0.f;
    for(int b=0;b<NB;b++){ fs += nll[b] / (float)TT; bs += gsum[b] / (float)TF; }
    out[6400] = -(bs / (float)NB);   // bin_loss
    out[6401] = fs / (float)NB;      // forwardsum_loss
  }
}

extern "C" void kernel_launch(void* const* d_in, const int* in_sizes, int n_in,
                              void* d_out, int out_size, void* d_ws, size_t ws_size,
                              hipStream_t stream){
  const float* speech = (const float*)d_in[0];
  const float* txt    = (const float*)d_in[1];
  const float* tw1 = (const float*)d_in[4];
  const float* tb1 = (const float*)d_in[5];
  const float* tw2 = (const float*)d_in[6];
  const float* tb2 = (const float*)d_in[7];
  const float* fw1 = (const float*)d_in[8];
  const float* fb1 = (const float*)d_in[9];
  const float* fw2 = (const float*)d_in[10];
  const float* fb2 = (const float*)d_in[11];
  const float* fw3 = (const float*)d_in[12];
  const float* fb3 = (const float*)d_in[13];
  float* out  = (float*)d_out;
  float* ds   = out;                 // (16,400)
  float* logp = out + 6402;          // (16,2000,400)
  char* ws = (char*)d_ws;
  double* lgt  = (double*)(ws + 0);
  double* rowA = (double*)(ws + 20480);
  double* colA = (double*)(ws + 36864);
  double* sA   = (double*)(ws + 40960);
  float*  nll  = (float*)(ws + 61440);
  float*  gsum = (float*)(ws + 61696);
  float*  Z2   = (float*)(ws + 65536);
  float*  fn2  = (float*)(ws + 196608);
  float*  tn2  = (float*)(ws + 327680);
  unsigned char* cmpb = (unsigned char*)(ws + 360448);
  float*  tenc = (float*)(ws + 2408448);
  float*  f1   = (float*)(ws + 8962048);
  float*  t1   = f1;      // t1 dead before f1 (f-conv1 out) is written
  float*  f2   = logp;    // f-conv2 intermediate; dead before scores written
  if(ws_size < 41730048) return;

  k_lgt  <<<10,256,0,stream>>>(lgt);
  k_terms<<<10,256,0,stream>>>(lgt,rowA,colA,sA);

  conv_k<256,3,true ><<<dim3(13,NB),256,0,stream>>>(txt, tw1, tb1, t1, TT);
  conv_k<256,1,false><<<dim3(13,NB),256,0,stream>>>(t1, tw2, tb2, tenc, TT);
  conv_k<512,3,true ><<<dim3(63,NB),256,0,stream>>>(speech, fw1, fb1, f1, TF);
  conv_k<256,3,true ><<<dim3(63,NB),256,0,stream>>>(f1, fw2, fb2, f2, TF);
  conv_k<256,1,false><<<dim3(63,NB),256,0,stream>>>(f2, fw3, fb3, f1, TF);

  norm2_k<<<(NB*TF)/4,256,0,stream>>>(f1, fn2, NB*TF);
  norm2_k<<<(NB*TT)/4,256,0,stream>>>(tenc, tn2, NB*TT);

  score_gemm<<<dim3(7,32,NB),256,0,stream>>>(f1, tenc, fn2, tn2, logp);
  softmax_prior_k<<<NB*TF,128,0,stream>>>(logp, rowA, colA, sA, Z2);

  scan_k<<<2*NB,64,0,stream>>>(logp, Z2, cmpb, nll);
  masback_k<<<NB,256,0,stream>>>(cmpb, logp, ds, gsum);
  final_k<<<1,64,0,stream>>>(nll, gsum, out);
}

// Round 7
// 1880.479 us; speedup vs baseline: 1.7492x; 1.5073x over previous
//
#include <hip/hip_runtime.h>
#include <math.h>

typedef unsigned int u32;
typedef unsigned long long u64;

#define BIGN (-1e30f)

static constexpr int NB = 16;     // batch
static constexpr int TF = 2000;   // T_FEATS
static constexpr int TT = 400;    // T_TEXT

__device__ __forceinline__ float wsum(float v){
#pragma unroll
  for(int o=32;o;o>>=1) v += __shfl_xor(v,o,64);
  return v;
}
// raw HW transcendentals: v_exp_f32 (2^x), v_log_f32 (log2 x)
__device__ __forceinline__ float EXP2(float x){ return __builtin_amdgcn_exp2f(x); }
__device__ __forceinline__ float LOG2(float x){ return __builtin_amdgcn_logf(x); }

// log-sum-exp in BASE-2 domain
__device__ __forceinline__ float lse2b(float x, float y){
  float m = fmaxf(x,y);
  return m + LOG2(1.0f + EXP2(-fabsf(x-y)));
}
__device__ __forceinline__ float lse3b(float x, float y, float z){
  float mx = fmaxf(fmaxf(x,y),z);
  float md = __builtin_amdgcn_fmed3f(x,y,z);
  float mn = fminf(fminf(x,y),z);
  return mx + LOG2(1.0f + EXP2(md-mx) + EXP2(mn-mx));
}

// ---------------- gammaln tables ----------------
__global__ void k_lgt(double* lgt){
  int m = blockIdx.x*blockDim.x + threadIdx.x;
  if(m < 2432) lgt[m] = (m>=1)? lgamma((double)m) : 0.0;
}
__global__ void k_terms(const double* __restrict__ lgt, double* rowA, double* colA, double* sA){
  int i = blockIdx.x*blockDim.x + threadIdx.x;
  if(i < TF)   rowA[i] = -lgt[2401] - lgt[i+1] - lgt[2000-i] + lgt[2001];
  if(i < TT)   colA[i] =  lgt[401]  - lgt[i+2] - lgt[400-i];
  if(i < 2399) sA[i]   =  lgt[i+2]  + lgt[2399-i];
}

// ---------------- conv1d (cross-correlation, pad=(KW-1)/2), OIH weights ----------------
// weights: per-thread register tiles (8 channels), double-buffered dwordx4 loads.
template<int CIN, int KW, bool RELU>
__global__ __launch_bounds__(256) void conv_k(const float* __restrict__ in, const float* __restrict__ w,
    const float* __restrict__ bias, float* __restrict__ out, int P){
  constexpr int PT = 32;
  constexpr int ROWS = PT + KW - 1;
  constexpr int RPAD = (ROWS + 3) & ~3;
  constexpr int CT = 8;
  constexpr int WT = CT*KW;            // 24 (KW3) or 8 (KW1)
  __shared__ __align__(16) float xs[256][RPAD];
  const int b = blockIdx.y;
  const int p0 = blockIdx.x * PT;
  const int o = threadIdx.x;
  float acc[PT];
  const float bo = bias[o];
#pragma unroll
  for(int i=0;i<PT;i++) acc[i] = bo;
  const float* inb = in + (size_t)b * P * CIN;
  const float* wo  = w  + (size_t)o * CIN * KW;
  for(int cc=0; cc<CIN; cc+=256){
    __syncthreads();
    for(int i=0;i<ROWS;i++){
      int p = p0 + i - (KW==3 ? 1 : 0);
      float v = 0.f;
      if(p>=0 && p<P) v = inb[(size_t)p*CIN + cc + o];
      xs[o][i] = v;
    }
    __syncthreads();
    float wA[WT], wB[WT];
#pragma unroll
    for(int q=0;q<WT/4;q++) ((float4*)wA)[q] = ((const float4*)(wo + (size_t)cc*KW))[q];
    for(int c0=0; c0<256; c0+=2*CT){
#pragma unroll
      for(int q=0;q<WT/4;q++) ((float4*)wB)[q] = ((const float4*)(wo + (size_t)(cc+c0+CT)*KW))[q];
#pragma unroll
      for(int c=0;c<CT;c++){
        float win[RPAD];
#pragma unroll
        for(int q=0;q<RPAD/4;q++) ((float4*)win)[q] = ((const float4*)&xs[c0+c][0])[q];
        if(KW==3){
          float w0=wA[c*3], w1=wA[c*3+1], w2=wA[c*3+2];
#pragma unroll
          for(int i=0;i<PT;i++) acc[i] = fmaf(w2,win[i+2],fmaf(w1,win[i+1],fmaf(w0,win[i],acc[i])));
        } else {
          float w0=wA[c];
#pragma unroll
          for(int i=0;i<PT;i++) acc[i] = fmaf(w0,win[i],acc[i]);
        }
      }
      int cn = (c0+2*CT < 256)? (cc+c0+2*CT) : cc;   // clamp: dummy reload on last pair
#pragma unroll
      for(int q=0;q<WT/4;q++) ((float4*)wA)[q] = ((const float4*)(wo + (size_t)cn*KW))[q];
#pragma unroll
      for(int c=0;c<CT;c++){
        float win[RPAD];
#pragma unroll
        for(int q=0;q<RPAD/4;q++) ((float4*)win)[q] = ((const float4*)&xs[c0+CT+c][0])[q];
        if(KW==3){
          float w0=wB[c*3], w1=wB[c*3+1], w2=wB[c*3+2];
#pragma unroll
          for(int i=0;i<PT;i++) acc[i] = fmaf(w2,win[i+2],fmaf(w1,win[i+1],fmaf(w0,win[i],acc[i])));
        } else {
          float w0=wB[c];
#pragma unroll
          for(int i=0;i<PT;i++) acc[i] = fmaf(w0,win[i],acc[i]);
        }
      }
    }
  }
#pragma unroll
  for(int i=0;i<PT;i++){
    int p = p0+i;
    if(p<P){
      float v = acc[i];
      if(RELU) v = fmaxf(v,0.f);
      out[((size_t)b*P+p)*256 + o] = v;
    }
  }
}

// ---------------- row squared norms ----------------
__global__ __launch_bounds__(256) void norm2_k(const float* __restrict__ x, float* __restrict__ o, int rows){
  int r = blockIdx.x*4 + (threadIdx.x>>6);
  int lane = threadIdx.x & 63;
  if(r>=rows) return;
  float4 v = ((const float4*)(x + (size_t)r*256))[lane];
  float s = v.x*v.x + v.y*v.y + v.z*v.z + v.w*v.w;
  s = wsum(s);
  if(lane==0) o[r] = s;
}

// ---------------- score = -sqrt(max(||f||^2+||t||^2-2 f.t, 1e-12)) ----------------
__global__ __launch_bounds__(256) void score_gemm(const float* __restrict__ F, const float* __restrict__ Tn,
    const float* __restrict__ fn2, const float* __restrict__ tn2, float* __restrict__ outp){
  constexpr int KC = 32;
  __shared__ __align__(16) float As[KC][68];
  __shared__ __align__(16) float Bs[KC][68];
  const int b = blockIdx.z;
  const int t0 = blockIdx.y*64, s0 = blockIdx.x*64;
  const int tid = threadIdx.x, tx = tid&15, ty = tid>>4;
  const float* Fb = F  + (size_t)b*TF*256;
  const float* Tb = Tn + (size_t)b*TT*256;
  float acc[4][4] = {};
  const int lk = tid & 31, lt0 = (tid>>5)*8;
  for(int k0=0;k0<256;k0+=KC){
    __syncthreads();
#pragma unroll
    for(int i=0;i<8;i++){
      int t = t0 + lt0 + i;
      As[lk][lt0+i] = (t<TF)? Fb[(size_t)t*256 + k0 + lk] : 0.f;
      int s = s0 + lt0 + i;
      Bs[lk][lt0+i] = (s<TT)? Tb[(size_t)s*256 + k0 + lk] : 0.f;
    }
    __syncthreads();
#pragma unroll
    for(int k=0;k<KC;k++){
      float a0[4], b0[4];
      *(float4*)a0 = *(const float4*)&As[k][ty*4];
      *(float4*)b0 = *(const float4*)&Bs[k][tx*4];
#pragma unroll
      for(int i=0;i<4;i++)
#pragma unroll
        for(int j=0;j<4;j++) acc[i][j] = fmaf(a0[i], b0[j], acc[i][j]);
    }
  }
#pragma unroll
  for(int i=0;i<4;i++){
    int t = t0 + ty*4 + i;
    if(t<TF){
      float fn = fn2[b*TF + t];
#pragma unroll
      for(int j=0;j<4;j++){
        int s = s0 + tx*4 + j;
        if(s<TT){
          float d2 = fn + tn2[b*TT + s] - 2.f*acc[i][j];
          outp[((size_t)b*TF + t)*TT + s] = -sqrtf(fmaxf(d2, 1e-12f));
        }
      }
    }
  }
}

// ---------------- per-row log_softmax + prior, and Z2 = logsumexp([BLANK, row]) ----------------
__global__ __launch_bounds__(128) void softmax_prior_k(float* __restrict__ logp,
    const double* __restrict__ rowA, const double* __restrict__ colA, const double* __restrict__ sA,
    float* __restrict__ Z2){
  const int row = blockIdx.x;           // b*TF + t0
  const int t0 = row % TF;
  float* rp = logp + (size_t)row*TT;
  const int tid = threadIdx.x;
  __shared__ float sh2[2];
  float v[4]; int ix[4];
#pragma unroll
  for(int i=0;i<4;i++){ ix[i] = tid + i*128; v[i] = (ix[i]<TT)? rp[ix[i]] : BIGN; }
  float m = fmaxf(fmaxf(v[0],v[1]),fmaxf(v[2],v[3]));
#pragma unroll
  for(int o=32;o;o>>=1) m = fmaxf(m, __shfl_xor(m,o,64));
  if((tid&63)==0) sh2[tid>>6] = m;
  __syncthreads();
  m = fmaxf(sh2[0], sh2[1]);
  float s = 0.f;
#pragma unroll
  for(int i=0;i<4;i++) if(ix[i]<TT) s += __expf(v[i]-m);
  s = wsum(s);
  __syncthreads();
  if((tid&63)==0) sh2[tid>>6] = s;
  __syncthreads();
  s = sh2[0] + sh2[1];
  const float lse = m + __logf(s);
  const double rA = rowA[t0];
  float f[4]; float m2 = BIGN;
#pragma unroll
  for(int i=0;i<4;i++){
    if(ix[i]<TT){
      float pr = (float)(colA[ix[i]] + sA[t0+ix[i]] + rA);
      f[i] = (v[i]-lse) + pr;
      rp[ix[i]] = f[i];
      m2 = fmaxf(m2, f[i]);
    } else f[i] = BIGN;
  }
#pragma unroll
  for(int o=32;o;o>>=1) m2 = fmaxf(m2, __shfl_xor(m2,o,64));
  __syncthreads();
  if((tid&63)==0) sh2[tid>>6] = m2;
  __syncthreads();
  m2 = fmaxf(fmaxf(sh2[0],sh2[1]), -1.0f);
  float s2 = (tid==0)? __expf(-1.0f - m2) : 0.f;
#pragma unroll
  for(int i=0;i<4;i++) if(ix[i]<TT) s2 += __expf(f[i]-m2);
  s2 = wsum(s2);
  __syncthreads();
  if((tid&63)==0) sh2[tid>>6] = s2;
  __syncthreads();
  if(tid==0) Z2[row] = m2 + __logf(sh2[0]+sh2[1]);
}

// ---------------- single-wave scans: CTC forward (log2 domain) + MAS ----------------
#define LCTC_STEP(E) { \
  float n1 = __shfl_up(a[13], 1); \
  if(lane==0) n1 = BIGN; \
  a[13] = lse3b(a[13], a[12], a[11]) + (E)[6]; \
  a[12] = lse2b(a[12], a[11]) + EBL; \
  a[11] = lse3b(a[11], a[10], a[9]) + (E)[5]; \
  a[10] = lse2b(a[10], a[9]) + EBL; \
  a[9]  = lse3b(a[9],  a[8],  a[7]) + (E)[4]; \
  a[8]  = lse2b(a[8],  a[7]) + EBL; \
  a[7]  = lse3b(a[7],  a[6],  a[5]) + (E)[3]; \
  a[6]  = lse2b(a[6],  a[5]) + EBL; \
  a[5]  = lse3b(a[5],  a[4],  a[3]) + (E)[2]; \
  a[4]  = lse2b(a[4],  a[3]) + EBL; \
  a[3]  = lse3b(a[3],  a[2],  a[1]) + (E)[1]; \
  a[2]  = lse2b(a[2],  a[1]) + EBL; \
  a[1]  = lse3b(a[1],  a[0],  n1) + (E)[0]; \
  a[0]  = lse2b(a[0],  n1) + EBL; }

#define CPREF(E, ROW) { int rr=(ROW); rr = (rr>TF-1)? (TF-1) : rr; const float* rpp = lp + (size_t)rr*TT; \
  (E)[0]=rpp[jc[0]]*IL2; (E)[1]=rpp[jc[1]]*IL2; (E)[2]=rpp[jc[2]]*IL2; (E)[3]=rpp[jc[3]]*IL2; \
  (E)[4]=rpp[jc[4]]*IL2; (E)[5]=rpp[jc[5]]*IL2; (E)[6]=rpp[jc[6]]*IL2; }

#define MAS_STEP(E, TIDX) { \
  float n1 = __shfl_up(q[6],1); \
  u32 byte = 0; \
  if(lane>0 && n1 >= q[0]) byte |= 1u; \
  if(q[0] >= q[1]) byte |= 2u; \
  if(q[1] >= q[2]) byte |= 4u; \
  if(q[2] >= q[3]) byte |= 8u; \
  if(q[3] >= q[4]) byte |= 16u; \
  if(q[4] >= q[5]) byte |= 32u; \
  if(q[5] >= q[6]) byte |= 64u; \
  cb[(size_t)((TIDX)-1)*64 + lane] = (unsigned char)byte; \
  q[6] = fmaxf(q[6], q[5]) + (E)[6]; \
  q[5] = fmaxf(q[5], q[4]) + (E)[5]; \
  q[4] = fmaxf(q[4], q[3]) + (E)[4]; \
  q[3] = fmaxf(q[3], q[2]) + (E)[3]; \
  q[2] = fmaxf(q[2], q[1]) + (E)[2]; \
  q[1] = fmaxf(q[1], q[0]) + (E)[1]; \
  q[0] = fmaxf(q[0], (lane>0)? n1 : BIGN) + (E)[0]; }

#define MPREF(E, ROW) { int rr=(ROW); rr = (rr>TF-1)? (TF-1) : rr; const float* rpp = lp + (size_t)rr*TT; \
  (E)[0]=rpp[jc[0]]; (E)[1]=rpp[jc[1]]; (E)[2]=rpp[jc[2]]; (E)[3]=rpp[jc[3]]; \
  (E)[4]=rpp[jc[4]]; (E)[5]=rpp[jc[5]]; (E)[6]=rpp[jc[6]]; }

__global__ __launch_bounds__(64) __attribute__((amdgpu_waves_per_eu(1,1)))
void scan_k(const float* __restrict__ logp,
    const float* __restrict__ Z2, unsigned char* __restrict__ cmpb, float* __restrict__ nll){
  const int lane = threadIdx.x;
  constexpr float IL2 = 1.4426950408889634f;   // 1/ln2
  constexpr float L2  = 0.6931471805599453f;   // ln2
  if(blockIdx.x < NB){
    const int b = blockIdx.x;
    const float* lp = logp + (size_t)b*TF*TT;
    double zs = 0.0;
    for(int t=lane; t<TF; t+=64) zs += (double)Z2[b*TF + t];
#pragma unroll
    for(int o=32;o;o>>=1) zs += __shfl_xor(zs, o, 64);
    int jc[7];
#pragma unroll
    for(int i=0;i<7;i++){ int j = 7*lane + i; jc[i] = (j < TT)? j : (TT-1); }
    float a[14];
#pragma unroll
    for(int i=0;i<14;i++) a[i] = BIGN;
    if(lane==0){ a[0] = -1.0f*IL2; a[1] = lp[0]*IL2; }
    const float EBL = -1.0f*IL2;
    float e0[7],e1[7],e2[7],e3[7],e4[7],e5[7],e6[7],e7[7];
    CPREF(e0,1); CPREF(e1,2); CPREF(e2,3); CPREF(e3,4);
    CPREF(e4,5); CPREF(e5,6); CPREF(e6,7); CPREF(e7,8);
    int t0 = 1;
    for(; t0 + 8 <= TF; t0 += 8){
      LCTC_STEP(e0); CPREF(e0, t0+8);
      LCTC_STEP(e1); CPREF(e1, t0+9);
      LCTC_STEP(e2); CPREF(e2, t0+10);
      LCTC_STEP(e3); CPREF(e3, t0+11);
      LCTC_STEP(e4); CPREF(e4, t0+12);
      LCTC_STEP(e5); CPREF(e5, t0+13);
      LCTC_STEP(e6); CPREF(e6, t0+14);
      LCTC_STEP(e7); CPREF(e7, t0+15);
    }
    for(; t0<TF; t0++){     // short tail, direct loads
      float P[7];
      CPREF(P, t0);
      LCTC_STEP(P);
    }
    if(lane==57){
      float r = lse2b(a[2], a[1]) * L2;  // states 800, 799
      nll[b] = -(r - (float)zs);
    }
  } else {
    const int b = blockIdx.x - NB;
    const float* lp = logp + (size_t)b*TF*TT;
    unsigned char* cb = cmpb + (size_t)b*TF*64;
    int jc[7];
#pragma unroll
    for(int i=0;i<7;i++){ int j = 7*lane + i; jc[i] = (j < TT)? j : (TT-1); }
    float q[7];
#pragma unroll
    for(int i=0;i<7;i++) q[i] = BIGN;
    if(lane==0) q[0] = lp[0];
    float e0[7],e1[7],e2[7],e3[7];
    MPREF(e0,1); MPREF(e1,2); MPREF(e2,3); MPREF(e3,4);
    int t0 = 1;
    for(; t0 + 4 <= TF; t0 += 4){
      MAS_STEP(e0, t0);   MPREF(e0, t0+4);
      MAS_STEP(e1, t0+1); MPREF(e1, t0+5);
      MAS_STEP(e2, t0+2); MPREF(e2, t0+6);
      MAS_STEP(e3, t0+3); MPREF(e3, t0+7);
    }
    for(; t0<TF; t0++){
      float P[7];
      MPREF(P, t0);
      MAS_STEP(P, t0);
    }
    // final row of cmp bits (row TF-1)
    {
      float n1 = __shfl_up(q[6],1);
      u32 byte = 0;
      if(lane>0 && n1 >= q[0]) byte |= 1u;
      if(q[0] >= q[1]) byte |= 2u;
      if(q[1] >= q[2]) byte |= 4u;
      if(q[2] >= q[3]) byte |= 8u;
      if(q[3] >= q[4]) byte |= 16u;
      if(q[4] >= q[5]) byte |= 32u;
      if(q[5] >= q[6]) byte |= 64u;
      cb[(size_t)(TF-1)*64 + lane] = (unsigned char)byte;
    }
  }
}

// ---------------- MAS backtrack + ds + gather ----------------
__global__ __launch_bounds__(256) void masback_k(const unsigned char* __restrict__ cmpb,
    const float* __restrict__ logp, float* __restrict__ ds, float* __restrict__ gsum){
  const int b = blockIdx.x;
  const unsigned char* cb = cmpb + (size_t)b*TF*64;
  __shared__ unsigned char bits[500*64];
  __shared__ short Ash[TF];
  __shared__ int cnt[TT];
  __shared__ float ps[4];
  int a = TT-1;
  for(int ch=3; ch>=0; ch--){
    const int tlo = ch*500;
    __syncthreads();
    for(int i=threadIdx.x;i<8000;i+=256) ((u32*)bits)[i] = ((const u32*)(cb + (size_t)tlo*64))[i];
    __syncthreads();
    if(threadIdx.x==0){
      int thi = tlo + 499;
      if(ch==3){ Ash[TF-1] = (short)(TT-1); thi = TF-2; }
      for(int t=thi;t>=tlo;t--){
        if(a > 0){
          unsigned char w = bits[(t-tlo)*64 + a/7];
          a -= (int)((w >> (a%7)) & 1u);
        }
        Ash[t] = (short)a;
      }
    }
  }
  __syncthreads();
  for(int i=threadIdx.x;i<TT;i+=256) cnt[i]=0;
  __syncthreads();
  float part = 0.f;
  const float* lp = logp + (size_t)b*TF*TT;
  for(int t=threadIdx.x;t<TF;t+=256){
    int at = Ash[t];
    atomicAdd(&cnt[at], 1);
    part += lp[(size_t)t*TT + at];
  }
  __syncthreads();
  for(int i=threadIdx.x;i<TT;i+=256) ds[(size_t)b*TT + i] = (float)cnt[i];
  part = wsum(part);
  if((threadIdx.x&63)==0) ps[threadIdx.x>>6] = part;
  __syncthreads();
  if(threadIdx.x==0) gsum[b] = ps[0]+ps[1]+ps[2]+ps[3];
}

__global__ void final_k(const float* __restrict__ nll, const float* __restrict__ gsum, float* __restrict__ out){
  if(threadIdx.x==0 && blockIdx.x==0){
    float fs=0.f, bs=0.f;
    for(int b=0;b<NB;b++){ fs += nll[b] / (float)TT; bs += gsum[b] / (float)TF; }
    out[6400] = -(bs / (float)NB);   // bin_loss
    out[6401] = fs / (float)NB;      // forwardsum_loss
  }
}

extern "C" void kernel_launch(void* const* d_in, const int* in_sizes, int n_in,
                              void* d_out, int out_size, void* d_ws, size_t ws_size,
                              hipStream_t stream){
  const float* speech = (const float*)d_in[0];
  const float* txt    = (const float*)d_in[1];
  const float* tw1 = (const float*)d_in[4];
  const float* tb1 = (const float*)d_in[5];
  const float* tw2 = (const float*)d_in[6];
  const float* tb2 = (const float*)d_in[7];
  const float* fw1 = (const float*)d_in[8];
  const float* fb1 = (const float*)d_in[9];
  const float* fw2 = (const float*)d_in[10];
  const float* fb2 = (const float*)d_in[11];
  const float* fw3 = (const float*)d_in[12];
  const float* fb3 = (const float*)d_in[13];
  float* out  = (float*)d_out;
  float* ds   = out;                 // (16,400)
  float* logp = out + 6402;          // (16,2000,400)
  char* ws = (char*)d_ws;
  double* lgt  = (double*)(ws + 0);
  double* rowA = (double*)(ws + 20480);
  double* colA = (double*)(ws + 36864);
  double* sA   = (double*)(ws + 40960);
  float*  nll  = (float*)(ws + 61440);
  float*  gsum = (float*)(ws + 61696);
  float*  Z2   = (float*)(ws + 65536);
  float*  fn2  = (float*)(ws + 196608);
  float*  tn2  = (float*)(ws + 327680);
  unsigned char* cmpb = (unsigned char*)(ws + 360448);
  float*  tenc = (float*)(ws + 2408448);
  float*  f1   = (float*)(ws + 8962048);
  float*  t1   = f1;      // t1 dead before f1 (f-conv1 out) is written
  float*  f2   = logp;    // f-conv2 intermediate; dead before scores written
  if(ws_size < 41730048) return;

  k_lgt  <<<10,256,0,stream>>>(lgt);
  k_terms<<<10,256,0,stream>>>(lgt,rowA,colA,sA);

  conv_k<256,3,true ><<<dim3(13,NB),256,0,stream>>>(txt, tw1, tb1, t1, TT);
  conv_k<256,1,false><<<dim3(13,NB),256,0,stream>>>(t1, tw2, tb2, tenc, TT);
  conv_k<512,3,true ><<<dim3(63,NB),256,0,stream>>>(speech, fw1, fb1, f1, TF);
  conv_k<256,3,true ><<<dim3(63,NB),256,0,stream>>>(f1, fw2, fb2, f2, TF);
  conv_k<256,1,false><<<dim3(63,NB),256,0,stream>>>(f2, fw3, fb3, f1, TF);

  norm2_k<<<(NB*TF)/4,256,0,stream>>>(f1, fn2, NB*TF);
  norm2_k<<<(NB*TT)/4,256,0,stream>>>(tenc, tn2, NB*TT);

  score_gemm<<<dim3(7,32,NB),256,0,stream>>>(f1, tenc, fn2, tn2, logp);
  softmax_prior_k<<<NB*TF,128,0,stream>>>(logp, rowA, colA, sA, Z2);

  scan_k<<<2*NB,64,0,stream>>>(logp, Z2, cmpb, nll);
  masback_k<<<NB,256,0,stream>>>(cmpb, logp, ds, gsum);
  final_k<<<1,64,0,stream>>>(nll, gsum, out);
}

// Round 8
// 1553.030 us; speedup vs baseline: 2.1180x; 1.2108x over previous
//
#include <hip/hip_runtime.h>
#include <math.h>

typedef unsigned int u32;
typedef unsigned long long u64;

#define BIGN (-1e30f)

static constexpr int NB = 16;     // batch
static constexpr int TF = 2000;   // T_FEATS
static constexpr int TT = 400;    // T_TEXT

__device__ __forceinline__ float wsum(float v){
#pragma unroll
  for(int o=32;o;o>>=1) v += __shfl_xor(v,o,64);
  return v;
}
// raw HW transcendentals: v_exp_f32 (2^x), v_log_f32 (log2 x)
__device__ __forceinline__ float EXP2(float x){ return __builtin_amdgcn_exp2f(x); }
__device__ __forceinline__ float LOG2(float x){ return __builtin_amdgcn_logf(x); }

// log-sum-exp in BASE-2 domain
__device__ __forceinline__ float lse2b(float x, float y){
  float m = fmaxf(x,y);
  return m + LOG2(1.0f + EXP2(-fabsf(x-y)));
}
__device__ __forceinline__ float lse3b(float x, float y, float z){
  float mx = fmaxf(fmaxf(x,y),z);
  float md = __builtin_amdgcn_fmed3f(x,y,z);
  float mn = fminf(fminf(x,y),z);
  return mx + LOG2(1.0f + EXP2(md-mx) + EXP2(mn-mx));
}

// ---------------- gammaln tables ----------------
__global__ void k_lgt(double* lgt){
  int m = blockIdx.x*blockDim.x + threadIdx.x;
  if(m < 2432) lgt[m] = (m>=1)? lgamma((double)m) : 0.0;
}
__global__ void k_terms(const double* __restrict__ lgt, double* rowA, double* colA, double* sA){
  int i = blockIdx.x*blockDim.x + threadIdx.x;
  if(i < TF)   rowA[i] = -lgt[2401] - lgt[i+1] - lgt[2000-i] + lgt[2001];
  if(i < TT)   colA[i] =  lgt[401]  - lgt[i+2] - lgt[400-i];
  if(i < 2399) sA[i]   =  lgt[i+2]  + lgt[2399-i];
}

// ---------------- conv1d (cross-correlation, pad=(KW-1)/2), OIH weights ----------------
// weights: per-thread register tiles (8 channels), double-buffered dwordx4 loads.
template<int CIN, int KW, bool RELU>
__global__ __launch_bounds__(256) void conv_k(const float* __restrict__ in, const float* __restrict__ w,
    const float* __restrict__ bias, float* __restrict__ out, int P){
  constexpr int PT = 32;
  constexpr int ROWS = PT + KW - 1;
  constexpr int RPAD = (ROWS + 3) & ~3;
  constexpr int CT = 8;
  constexpr int WT = CT*KW;            // 24 (KW3) or 8 (KW1)
  __shared__ __align__(16) float xs[256][RPAD];
  const int b = blockIdx.y;
  const int p0 = blockIdx.x * PT;
  const int o = threadIdx.x;
  float acc[PT];
  const float bo = bias[o];
#pragma unroll
  for(int i=0;i<PT;i++) acc[i] = bo;
  const float* inb = in + (size_t)b * P * CIN;
  const float* wo  = w  + (size_t)o * CIN * KW;
  for(int cc=0; cc<CIN; cc+=256){
    __syncthreads();
    for(int i=0;i<ROWS;i++){
      int p = p0 + i - (KW==3 ? 1 : 0);
      float v = 0.f;
      if(p>=0 && p<P) v = inb[(size_t)p*CIN + cc + o];
      xs[o][i] = v;
    }
    __syncthreads();
    float wA[WT], wB[WT];
#pragma unroll
    for(int q=0;q<WT/4;q++) ((float4*)wA)[q] = ((const float4*)(wo + (size_t)cc*KW))[q];
    for(int c0=0; c0<256; c0+=2*CT){
#pragma unroll
      for(int q=0;q<WT/4;q++) ((float4*)wB)[q] = ((const float4*)(wo + (size_t)(cc+c0+CT)*KW))[q];
#pragma unroll
      for(int c=0;c<CT;c++){
        float win[RPAD];
#pragma unroll
        for(int q=0;q<RPAD/4;q++) ((float4*)win)[q] = ((const float4*)&xs[c0+c][0])[q];
        if(KW==3){
          float w0=wA[c*3], w1=wA[c*3+1], w2=wA[c*3+2];
#pragma unroll
          for(int i=0;i<PT;i++) acc[i] = fmaf(w2,win[i+2],fmaf(w1,win[i+1],fmaf(w0,win[i],acc[i])));
        } else {
          float w0=wA[c];
#pragma unroll
          for(int i=0;i<PT;i++) acc[i] = fmaf(w0,win[i],acc[i]);
        }
      }
      int cn = (c0+2*CT < 256)? (cc+c0+2*CT) : cc;   // clamp: dummy reload on last pair
#pragma unroll
      for(int q=0;q<WT/4;q++) ((float4*)wA)[q] = ((const float4*)(wo + (size_t)cn*KW))[q];
#pragma unroll
      for(int c=0;c<CT;c++){
        float win[RPAD];
#pragma unroll
        for(int q=0;q<RPAD/4;q++) ((float4*)win)[q] = ((const float4*)&xs[c0+CT+c][0])[q];
        if(KW==3){
          float w0=wB[c*3], w1=wB[c*3+1], w2=wB[c*3+2];
#pragma unroll
          for(int i=0;i<PT;i++) acc[i] = fmaf(w2,win[i+2],fmaf(w1,win[i+1],fmaf(w0,win[i],acc[i])));
        } else {
          float w0=wB[c];
#pragma unroll
          for(int i=0;i<PT;i++) acc[i] = fmaf(w0,win[i],acc[i]);
        }
      }
    }
  }
#pragma unroll
  for(int i=0;i<PT;i++){
    int p = p0+i;
    if(p<P){
      float v = acc[i];
      if(RELU) v = fmaxf(v,0.f);
      out[((size_t)b*P+p)*256 + o] = v;
    }
  }
}

// ---------------- row squared norms ----------------
__global__ __launch_bounds__(256) void norm2_k(const float* __restrict__ x, float* __restrict__ o, int rows){
  int r = blockIdx.x*4 + (threadIdx.x>>6);
  int lane = threadIdx.x & 63;
  if(r>=rows) return;
  float4 v = ((const float4*)(x + (size_t)r*256))[lane];
  float s = v.x*v.x + v.y*v.y + v.z*v.z + v.w*v.w;
  s = wsum(s);
  if(lane==0) o[r] = s;
}

// ---------------- score = -sqrt(max(||f||^2+||t||^2-2 f.t, 1e-12)) ----------------
__global__ __launch_bounds__(256) void score_gemm(const float* __restrict__ F, const float* __restrict__ Tn,
    const float* __restrict__ fn2, const float* __restrict__ tn2, float* __restrict__ outp){
  constexpr int KC = 32;
  __shared__ __align__(16) float As[KC][68];
  __shared__ __align__(16) float Bs[KC][68];
  const int b = blockIdx.z;
  const int t0 = blockIdx.y*64, s0 = blockIdx.x*64;
  const int tid = threadIdx.x, tx = tid&15, ty = tid>>4;
  const float* Fb = F  + (size_t)b*TF*256;
  const float* Tb = Tn + (size_t)b*TT*256;
  float acc[4][4] = {};
  const int lk = tid & 31, lt0 = (tid>>5)*8;
  for(int k0=0;k0<256;k0+=KC){
    __syncthreads();
#pragma unroll
    for(int i=0;i<8;i++){
      int t = t0 + lt0 + i;
      As[lk][lt0+i] = (t<TF)? Fb[(size_t)t*256 + k0 + lk] : 0.f;
      int s = s0 + lt0 + i;
      Bs[lk][lt0+i] = (s<TT)? Tb[(size_t)s*256 + k0 + lk] : 0.f;
    }
    __syncthreads();
#pragma unroll
    for(int k=0;k<KC;k++){
      float a0[4], b0[4];
      *(float4*)a0 = *(const float4*)&As[k][ty*4];
      *(float4*)b0 = *(const float4*)&Bs[k][tx*4];
#pragma unroll
      for(int i=0;i<4;i++)
#pragma unroll
        for(int j=0;j<4;j++) acc[i][j] = fmaf(a0[i], b0[j], acc[i][j]);
    }
  }
#pragma unroll
  for(int i=0;i<4;i++){
    int t = t0 + ty*4 + i;
    if(t<TF){
      float fn = fn2[b*TF + t];
#pragma unroll
      for(int j=0;j<4;j++){
        int s = s0 + tx*4 + j;
        if(s<TT){
          float d2 = fn + tn2[b*TT + s] - 2.f*acc[i][j];
          outp[((size_t)b*TF + t)*TT + s] = -sqrtf(fmaxf(d2, 1e-12f));
        }
      }
    }
  }
}

// ---------------- per-row log_softmax + prior, and Z2 = logsumexp([BLANK, row]) ----------------
__global__ __launch_bounds__(128) void softmax_prior_k(float* __restrict__ logp,
    const double* __restrict__ rowA, const double* __restrict__ colA, const double* __restrict__ sA,
    float* __restrict__ Z2){
  const int row = blockIdx.x;           // b*TF + t0
  const int t0 = row % TF;
  float* rp = logp + (size_t)row*TT;
  const int tid = threadIdx.x;
  __shared__ float sh2[2];
  float v[4]; int ix[4];
#pragma unroll
  for(int i=0;i<4;i++){ ix[i] = tid + i*128; v[i] = (ix[i]<TT)? rp[ix[i]] : BIGN; }
  float m = fmaxf(fmaxf(v[0],v[1]),fmaxf(v[2],v[3]));
#pragma unroll
  for(int o=32;o;o>>=1) m = fmaxf(m, __shfl_xor(m,o,64));
  if((tid&63)==0) sh2[tid>>6] = m;
  __syncthreads();
  m = fmaxf(sh2[0], sh2[1]);
  float s = 0.f;
#pragma unroll
  for(int i=0;i<4;i++) if(ix[i]<TT) s += __expf(v[i]-m);
  s = wsum(s);
  __syncthreads();
  if((tid&63)==0) sh2[tid>>6] = s;
  __syncthreads();
  s = sh2[0] + sh2[1];
  const float lse = m + __logf(s);
  const double rA = rowA[t0];
  float f[4]; float m2 = BIGN;
#pragma unroll
  for(int i=0;i<4;i++){
    if(ix[i]<TT){
      float pr = (float)(colA[ix[i]] + sA[t0+ix[i]] + rA);
      f[i] = (v[i]-lse) + pr;
      rp[ix[i]] = f[i];
      m2 = fmaxf(m2, f[i]);
    } else f[i] = BIGN;
  }
#pragma unroll
  for(int o=32;o;o>>=1) m2 = fmaxf(m2, __shfl_xor(m2,o,64));
  __syncthreads();
  if((tid&63)==0) sh2[tid>>6] = m2;
  __syncthreads();
  m2 = fmaxf(fmaxf(sh2[0],sh2[1]), -1.0f);
  float s2 = (tid==0)? __expf(-1.0f - m2) : 0.f;
#pragma unroll
  for(int i=0;i<4;i++) if(ix[i]<TT) s2 += __expf(f[i]-m2);
  s2 = wsum(s2);
  __syncthreads();
  if((tid&63)==0) sh2[tid>>6] = s2;
  __syncthreads();
  if(tid==0) Z2[row] = m2 + __logf(sh2[0]+sh2[1]);
}

// ---------------- scans ----------------
// CTC blocks (0..15): BIDIRECTIONAL. Wave 0 runs alpha over t=0..999; wave 1 runs the reversed
//   lattice (w=800-s, identical transition structure: skip into odd w>=3) over t=1999..1000.
//   Combine at the seam via LDS: logP = LSE_v( [LSE_{u->v} alpha(999,u)] + gamma(1000,v) ).
//   Serial length 1999 -> 999 steps.
// MAS blocks (16..31): wave 0 only, full 2000 steps (cheap per step), cmp bits 1 byte/lane/step.
#define LCTC_STEP(E) { \
  float n1 = __shfl_up(a[13], 1); \
  if(lane==0) n1 = BIGN; \
  a[13] = lse3b(a[13], a[12], a[11]) + (E)[6]; \
  a[12] = lse2b(a[12], a[11]) + EBL; \
  a[11] = lse3b(a[11], a[10], a[9]) + (E)[5]; \
  a[10] = lse2b(a[10], a[9]) + EBL; \
  a[9]  = lse3b(a[9],  a[8],  a[7]) + (E)[4]; \
  a[8]  = lse2b(a[8],  a[7]) + EBL; \
  a[7]  = lse3b(a[7],  a[6],  a[5]) + (E)[3]; \
  a[6]  = lse2b(a[6],  a[5]) + EBL; \
  a[5]  = lse3b(a[5],  a[4],  a[3]) + (E)[2]; \
  a[4]  = lse2b(a[4],  a[3]) + EBL; \
  a[3]  = lse3b(a[3],  a[2],  a[1]) + (E)[1]; \
  a[2]  = lse2b(a[2],  a[1]) + EBL; \
  a[1]  = lse3b(a[1],  a[0],  n1) + (E)[0]; \
  a[0]  = lse2b(a[0],  n1) + EBL; }

// step index K in 1..999; row = dir? TF-1-K : K
#define CPREF(E, K) { int kk=(K); if(kk>999) kk=999; int row = dir? (TF-1-kk) : kk; \
  const float* rpp = lp + (size_t)row*TT; \
  (E)[0]=rpp[jc[0]]*IL2; (E)[1]=rpp[jc[1]]*IL2; (E)[2]=rpp[jc[2]]*IL2; (E)[3]=rpp[jc[3]]*IL2; \
  (E)[4]=rpp[jc[4]]*IL2; (E)[5]=rpp[jc[5]]*IL2; (E)[6]=rpp[jc[6]]*IL2; }

#define MAS_STEP(E, TIDX) { \
  float n1 = __shfl_up(q[6],1); \
  u32 byte = 0; \
  if(lane>0 && n1 >= q[0]) byte |= 1u; \
  if(q[0] >= q[1]) byte |= 2u; \
  if(q[1] >= q[2]) byte |= 4u; \
  if(q[2] >= q[3]) byte |= 8u; \
  if(q[3] >= q[4]) byte |= 16u; \
  if(q[4] >= q[5]) byte |= 32u; \
  if(q[5] >= q[6]) byte |= 64u; \
  cb[(size_t)((TIDX)-1)*64 + lane] = (unsigned char)byte; \
  q[6] = fmaxf(q[6], q[5]) + (E)[6]; \
  q[5] = fmaxf(q[5], q[4]) + (E)[5]; \
  q[4] = fmaxf(q[4], q[3]) + (E)[4]; \
  q[3] = fmaxf(q[3], q[2]) + (E)[3]; \
  q[2] = fmaxf(q[2], q[1]) + (E)[2]; \
  q[1] = fmaxf(q[1], q[0]) + (E)[1]; \
  q[0] = fmaxf(q[0], (lane>0)? n1 : BIGN) + (E)[0]; }

#define MPREF(E, ROW) { int rr=(ROW); rr = (rr>TF-1)? (TF-1) : rr; const float* rpp = lp + (size_t)rr*TT; \
  (E)[0]=rpp[jc[0]]; (E)[1]=rpp[jc[1]]; (E)[2]=rpp[jc[2]]; (E)[3]=rpp[jc[3]]; \
  (E)[4]=rpp[jc[4]]; (E)[5]=rpp[jc[5]]; (E)[6]=rpp[jc[6]]; }

__global__ __launch_bounds__(128) __attribute__((amdgpu_waves_per_eu(1,1)))
void scan_k(const float* __restrict__ logp,
    const float* __restrict__ Z2, unsigned char* __restrict__ cmpb, float* __restrict__ nll){
  const int lane = threadIdx.x & 63;
  const int wave = threadIdx.x >> 6;
  constexpr float IL2 = 1.4426950408889634f;   // 1/ln2
  constexpr float L2  = 0.6931471805599453f;   // ln2
  if(blockIdx.x < NB){
    const int b = blockIdx.x;
    const float* lp = logp + (size_t)b*TF*TT;
    __shared__ float af[801], ag[801];
    const int dir = wave;                      // 0: t=0..999 ; 1: t=1999..1000 (state w=800-s)
    double zs = 0.0;
    if(wave==0){
      for(int t=lane; t<TF; t+=64) zs += (double)Z2[b*TF + t];
#pragma unroll
      for(int o=32;o;o>>=1) zs += __shfl_xor(zs, o, 64);
    }
    int jc[7];
#pragma unroll
    for(int i=0;i<7;i++){ int j = 7*lane + i; j = (j < TT)? j : (TT-1); jc[i] = dir? (TT-1-j) : j; }
    float a[14];
#pragma unroll
    for(int i=0;i<14;i++) a[i] = BIGN;
    if(lane==0){
      a[0] = -1.0f*IL2;                                           // blank end-state (s=0 / s=800)
      a[1] = (dir? lp[(size_t)(TF-1)*TT + (TT-1)] : lp[0]) * IL2; // emit end-state (s=1 / s=799)
    }
    const float EBL = -1.0f*IL2;
    float e0[7],e1[7],e2[7],e3[7],e4[7],e5[7],e6[7],e7[7];
    CPREF(e0,1); CPREF(e1,2); CPREF(e2,3); CPREF(e3,4);
    CPREF(e4,5); CPREF(e5,6); CPREF(e6,7); CPREF(e7,8);
    int k = 1;
    for(; k + 8 <= 993; k += 8){
      LCTC_STEP(e0); CPREF(e0, k+8);
      LCTC_STEP(e1); CPREF(e1, k+9);
      LCTC_STEP(e2); CPREF(e2, k+10);
      LCTC_STEP(e3); CPREF(e3, k+11);
      LCTC_STEP(e4); CPREF(e4, k+12);
      LCTC_STEP(e5); CPREF(e5, k+13);
      LCTC_STEP(e6); CPREF(e6, k+14);
      LCTC_STEP(e7); CPREF(e7, k+15);
    }
    for(; k<=999; k++){          // tail, direct loads
      float P[7];
      CPREF(P, k);
      LCTC_STEP(P);
    }
    float* dst = wave? ag : af;
#pragma unroll
    for(int i=0;i<14;i++){ int s = 14*lane+i; if(s<=800) dst[s] = a[i]; }
    __syncthreads();
    if(wave==0){
      float acc = BIGN;
#pragma unroll
      for(int i=0;i<14;i++){
        int s = 14*lane+i;
        if(s<=800){
          float x0 = af[s];
          float x1 = (s>=1)? af[s-1] : BIGN;
          float x2 = ((s&1) && s>=3)? af[s-2] : BIGN;
          float A1 = lse3b(x0,x1,x2);                 // one transition, no emission
          acc = lse2b(acc, A1 + ag[800-s]);
        }
      }
#pragma unroll
      for(int o=32;o;o>>=1) acc = lse2b(acc, __shfl_xor(acc,o,64));
      if(lane==0) nll[b] = -((acc*L2) - (float)zs);
    }
  } else {
    if(wave) return;
    const int b = blockIdx.x - NB;
    const float* lp = logp + (size_t)b*TF*TT;
    unsigned char* cb = cmpb + (size_t)b*TF*64;
    int jc[7];
#pragma unroll
    for(int i=0;i<7;i++){ int j = 7*lane + i; jc[i] = (j < TT)? j : (TT-1); }
    float q[7];
#pragma unroll
    for(int i=0;i<7;i++) q[i] = BIGN;
    if(lane==0) q[0] = lp[0];
    float e0[7],e1[7],e2[7],e3[7];
    MPREF(e0,1); MPREF(e1,2); MPREF(e2,3); MPREF(e3,4);
    int t0 = 1;
    for(; t0 + 4 <= TF; t0 += 4){
      MAS_STEP(e0, t0);   MPREF(e0, t0+4);
      MAS_STEP(e1, t0+1); MPREF(e1, t0+5);
      MAS_STEP(e2, t0+2); MPREF(e2, t0+6);
      MAS_STEP(e3, t0+3); MPREF(e3, t0+7);
    }
    for(; t0<TF; t0++){
      float P[7];
      MPREF(P, t0);
      MAS_STEP(P, t0);
    }
    // final row of cmp bits (row TF-1)
    {
      float n1 = __shfl_up(q[6],1);
      u32 byte = 0;
      if(lane>0 && n1 >= q[0]) byte |= 1u;
      if(q[0] >= q[1]) byte |= 2u;
      if(q[1] >= q[2]) byte |= 4u;
      if(q[2] >= q[3]) byte |= 8u;
      if(q[3] >= q[4]) byte |= 16u;
      if(q[4] >= q[5]) byte |= 32u;
      if(q[5] >= q[6]) byte |= 64u;
      cb[(size_t)(TF-1)*64 + lane] = (unsigned char)byte;
    }
  }
}

// ---------------- MAS backtrack + ds + gather ----------------
__global__ __launch_bounds__(256) void masback_k(const unsigned char* __restrict__ cmpb,
    const float* __restrict__ logp, float* __restrict__ ds, float* __restrict__ gsum){
  const int b = blockIdx.x;
  const unsigned char* cb = cmpb + (size_t)b*TF*64;
  __shared__ unsigned char bits[500*64];
  __shared__ short Ash[TF];
  __shared__ int cnt[TT];
  __shared__ float ps[4];
  int a = TT-1;
  for(int ch=3; ch>=0; ch--){
    const int tlo = ch*500;
    __syncthreads();
    for(int i=threadIdx.x;i<8000;i+=256) ((u32*)bits)[i] = ((const u32*)(cb + (size_t)tlo*64))[i];
    __syncthreads();
    if(threadIdx.x==0){
      int thi = tlo + 499;
      if(ch==3){ Ash[TF-1] = (short)(TT-1); thi = TF-2; }
      for(int t=thi;t>=tlo;t--){
        if(a > 0){
          unsigned char w = bits[(t-tlo)*64 + a/7];
          a -= (int)((w >> (a%7)) & 1u);
        }
        Ash[t] = (short)a;
      }
    }
  }
  __syncthreads();
  for(int i=threadIdx.x;i<TT;i+=256) cnt[i]=0;
  __syncthreads();
  float part = 0.f;
  const float* lp = logp + (size_t)b*TF*TT;
  for(int t=threadIdx.x;t<TF;t+=256){
    int at = Ash[t];
    atomicAdd(&cnt[at], 1);
    part += lp[(size_t)t*TT + at];
  }
  __syncthreads();
  for(int i=threadIdx.x;i<TT;i+=256) ds[(size_t)b*TT + i] = (float)cnt[i];
  part = wsum(part);
  if((threadIdx.x&63)==0) ps[threadIdx.x>>6] = part;
  __syncthreads();
  if(threadIdx.x==0) gsum[b] = ps[0]+ps[1]+ps[2]+ps[3];
}

__global__ void final_k(const float* __restrict__ nll, const float* __restrict__ gsum, float* __restrict__ out){
  if(threadIdx.x==0 && blockIdx.x==0){
    float fs=0.f, bs=0.f;
    for(int b=0;b<NB;b++){ fs += nll[b] / (float)TT; bs += gsum[b] / (float)TF; }
    out[6400] = -(bs / (float)NB);   // bin_loss
    out[6401] = fs / (float)NB;      // forwardsum_loss
  }
}

extern "C" void kernel_launch(void* const* d_in, const int* in_sizes, int n_in,
                              void* d_out, int out_size, void* d_ws, size_t ws_size,
                              hipStream_t stream){
  const float* speech = (const float*)d_in[0];
  const float* txt    = (const float*)d_in[1];
  const float* tw1 = (const float*)d_in[4];
  const float* tb1 = (const float*)d_in[5];
  const float* tw2 = (const float*)d_in[6];
  const float* tb2 = (const float*)d_in[7];
  const float* fw1 = (const float*)d_in[8];
  const float* fb1 = (const float*)d_in[9];
  const float* fw2 = (const float*)d_in[10];
  const float* fb2 = (const float*)d_in[11];
  const float* fw3 = (const float*)d_in[12];
  const float* fb3 = (const float*)d_in[13];
  float* out  = (float*)d_out;
  float* ds   = out;                 // (16,400)
  float* logp = out + 6402;          // (16,2000,400)
  char* ws = (char*)d_ws;
  double* lgt  = (double*)(ws + 0);
  double* rowA = (double*)(ws + 20480);
  double* colA = (double*)(ws + 36864);
  double* sA   = (double*)(ws + 40960);
  float*  nll  = (float*)(ws + 61440);
  float*  gsum = (float*)(ws + 61696);
  float*  Z2   = (float*)(ws + 65536);
  float*  fn2  = (float*)(ws + 196608);
  float*  tn2  = (float*)(ws + 327680);
  unsigned char* cmpb = (unsigned char*)(ws + 360448);
  float*  tenc = (float*)(ws + 2408448);
  float*  f1   = (float*)(ws + 8962048);
  float*  t1   = f1;      // t1 dead before f1 (f-conv1 out) is written
  float*  f2   = logp;    // f-conv2 intermediate; dead before scores written
  if(ws_size < 41730048) return;

  k_lgt  <<<10,256,0,stream>>>(lgt);
  k_terms<<<10,256,0,stream>>>(lgt,rowA,colA,sA);

  conv_k<256,3,true ><<<dim3(13,NB),256,0,stream>>>(txt, tw1, tb1, t1, TT);
  conv_k<256,1,false><<<dim3(13,NB),256,0,stream>>>(t1, tw2, tb2, tenc, TT);
  conv_k<512,3,true ><<<dim3(63,NB),256,0,stream>>>(speech, fw1, fb1, f1, TF);
  conv_k<256,3,true ><<<dim3(63,NB),256,0,stream>>>(f1, fw2, fb2, f2, TF);
  conv_k<256,1,false><<<dim3(63,NB),256,0,stream>>>(f2, fw3, fb3, f1, TF);

  norm2_k<<<(NB*TF)/4,256,0,stream>>>(f1, fn2, NB*TF);
  norm2_k<<<(NB*TT)/4,256,0,stream>>>(tenc, tn2, NB*TT);

  score_gemm<<<dim3(7,32,NB),256,0,stream>>>(f1, tenc, fn2, tn2, logp);
  softmax_prior_k<<<NB*TF,128,0,stream>>>(logp, rowA, colA, sA, Z2);

  scan_k<<<2*NB,128,0,stream>>>(logp, Z2, cmpb, nll);
  masback_k<<<NB,256,0,stream>>>(cmpb, logp, ds, gsum);
  final_k<<<1,64,0,stream>>>(nll, gsum, out);
}